// Round 8
// baseline (362.231 us; speedup 1.0000x reference)
//
#include <hip/hip_runtime.h>
#include <cstdint>

// Problem constants (from reference)
#define N_NODES 100000
#define N_EDGES 1600000
#define D_IN    128
#define D_H     64
#define D_OUT   16
#define M_TILES 6250  // N_NODES / 16

// Bucket sort parameters
#define NBKT   512
#define NPB    196           // nodes per bucket; 512*196 = 100352 >= N
#define BCAP   4096          // per-bucket region capacity (mean 3125, sd 56 -> +17 sigma)
#define TILE_E 4096          // edges per bin tile (256 thr x 16); N_EDGES % 16 == 0
#define NTILES ((N_EDGES + TILE_E - 1) / TILE_E)   // 391
#define G1     256           // bin-phase blocks inside the fused kernel
#define GEMM_BLOCKS ((M_TILES + 3) / 4)            // 1563
#define NCHUNK 391           // ceil(N_NODES / 256) node chunks for agg kernels

// Column-slice strides
#define HS_SLICE   (N_NODES * 8)   // ushorts per 8-col bf16 slice (1.6 MB)
#define H2S_SLICE  (N_NODES * 4)   // floats per 4-col f32 slice (1.6 MB)

typedef __attribute__((ext_vector_type(8))) short short8;
typedef __attribute__((ext_vector_type(4))) float floatx4;

// float -> bf16 bits (round to nearest even)
static __device__ __forceinline__ unsigned short f2bf(float f) {
    unsigned int u = __float_as_uint(f);
    u = u + 0x7FFFu + ((u >> 16) & 1u);
    return (unsigned short)(u >> 16);
}
static __device__ __forceinline__ float bf2f(unsigned short h) {
    return __uint_as_float(((unsigned int)h) << 16);
}

// ---------------------------------------------------------------------------
// Workspace layout (bytes, 128-aligned).
//   cursors : NBKT int          @ 0
//   offsets : N+1 int           @ 4096
//   dinv    : N float           @ 404224
//   srcs    : E+16 int (CSR)    @ 804224    (ends 7204288)
//   hs_cs   : 8 x N x 8 ushort  @ 7204352   (ends 20004352)  [col-sliced bf16]
//   h2s_cs  : 4 x N x 4 float   @ 20004480  (ends 26404480)  [col-sliced f32]
//   region  : NBKT*BCAP int     @ 26404480  (ends 34793088)
//   h_raw   : N*64 float        @ 34793088  (ends 60393088)  [raw x@W1]
//   agg_raw : N*64 float        @ 60393088  (ends 85993088)  [layer1 sums]
// total ~86 MB (workspace is 256 MB)
// ---------------------------------------------------------------------------

__global__ __launch_bounds__(512) void zero_small_kernel(int* __restrict__ cursors,
                                                         int* __restrict__ srcs) {
    cursors[threadIdx.x] = 0;
    if (threadIdx.x < 16) srcs[N_EDGES + threadIdx.x] = 0;
}

// ---------------------------------------------------------------------------
// FUSED prep + transform kernel (unchanged from r7, hardware-proven).
//   blocks [0, G1)          : edge binning (tile-synchronous LDS histogram)
//   blocks [G1, G1+GEMM)    : gemm1 via MFMA bf16x2, writes RAW f32 h
// ---------------------------------------------------------------------------
__global__ __launch_bounds__(256) void fused_bin_gemm1_kernel(
        const int* __restrict__ src, const int* __restrict__ dst,
        int* __restrict__ cursors, int* __restrict__ region,
        const float* __restrict__ x, const float* __restrict__ W1,
        float* __restrict__ h_raw) {
    __shared__ int hcnt[NBKT];
    __shared__ int hbase[NBKT];
    __shared__ unsigned short bhi_lds[8192];
    __shared__ unsigned short blo_lds[8192];

    const int t = threadIdx.x;

    if (blockIdx.x < G1) {
        // ---------------- bin phase ----------------
        for (int tile = blockIdx.x; tile < NTILES; tile += G1) {
            for (int i = t; i < NBKT; i += 256) hcnt[i] = 0;
            __syncthreads();
            int e0 = tile * TILE_E + t * 16;
            int pk[16], bk[16], rk[16];
            bool full = (e0 + 16 <= N_EDGES);
            if (full) {
                const int4* dp = (const int4*)(dst + e0);
                const int4* sp = (const int4*)(src + e0);
                int dv[16], sv[16];
                #pragma unroll
                for (int q = 0; q < 4; ++q) {
                    int4 d4 = dp[q]; int4 s4 = sp[q];
                    dv[4*q+0]=d4.x; dv[4*q+1]=d4.y; dv[4*q+2]=d4.z; dv[4*q+3]=d4.w;
                    sv[4*q+0]=s4.x; sv[4*q+1]=s4.y; sv[4*q+2]=s4.z; sv[4*q+3]=s4.w;
                }
                #pragma unroll
                for (int k = 0; k < 16; ++k) {
                    int d = dv[k];
                    int b = d / NPB;
                    bk[k] = b;
                    pk[k] = ((d - b * NPB) << 17) | sv[k];
                    rk[k] = atomicAdd(&hcnt[b], 1);
                }
            }
            __syncthreads();
            for (int i = t; i < NBKT; i += 256) {
                int c = hcnt[i];
                if (c > 0) hbase[i] = atomicAdd(&cursors[i], c);
            }
            __syncthreads();
            if (full) {
                #pragma unroll
                for (int k = 0; k < 16; ++k)
                    region[bk[k] * BCAP + hbase[bk[k]] + rk[k]] = pk[k];
            }
            __syncthreads();
        }
        return;
    }

    // ---------------- gemm1 phase ----------------
    for (int e = t; e < 8192; e += 256) {
        int j    = e & 7;
        int lane = (e >> 3) & 63;
        int pair = e >> 9;
        int kc   = pair >> 2;
        int nt   = pair & 3;
        int k = kc * 32 + (lane >> 4) * 8 + j;
        int n = nt * 16 + (lane & 15);
        float w = W1[k * D_H + n];
        unsigned short hi = f2bf(w);
        float lo = w - bf2f(hi);
        bhi_lds[e] = hi;
        blo_lds[e] = f2bf(lo);
    }
    __syncthreads();

    int wid  = t >> 6;
    int lane = t & 63;
    int quad = lane >> 4;
    int m    = lane & 15;

    int tile = (blockIdx.x - G1) * 4 + wid;
    if (tile >= M_TILES) return;
    int mbase = tile * 16;

    const float* xr = x + (size_t)(mbase + m) * D_IN + quad * 8;
    short8 ahi[4], alo[4];
    #pragma unroll
    for (int kc = 0; kc < 4; ++kc) {
        floatx4 v0 = *(const floatx4*)(xr + kc * 32);
        floatx4 v1 = *(const floatx4*)(xr + kc * 32 + 4);
        float f[8] = {v0.x, v0.y, v0.z, v0.w, v1.x, v1.y, v1.z, v1.w};
        #pragma unroll
        for (int j = 0; j < 8; ++j) {
            unsigned short hi = f2bf(f[j]);
            float lo = f[j] - bf2f(hi);
            ahi[kc][j] = (short)hi;
            alo[kc][j] = (short)f2bf(lo);
        }
    }

    floatx4 acc[4] = {{0.f,0.f,0.f,0.f},{0.f,0.f,0.f,0.f},{0.f,0.f,0.f,0.f},{0.f,0.f,0.f,0.f}};
    #pragma unroll
    for (int kc = 0; kc < 4; ++kc) {
        #pragma unroll
        for (int nt = 0; nt < 4; ++nt) {
            int fo = ((kc * 4 + nt) * 64 + lane) * 8;
            short8 bhi = *(const short8*)&bhi_lds[fo];
            short8 blo = *(const short8*)&blo_lds[fo];
            acc[nt] = __builtin_amdgcn_mfma_f32_16x16x32_bf16(ahi[kc], bhi, acc[nt], 0, 0, 0);
            acc[nt] = __builtin_amdgcn_mfma_f32_16x16x32_bf16(ahi[kc], blo, acc[nt], 0, 0, 0);
            acc[nt] = __builtin_amdgcn_mfma_f32_16x16x32_bf16(alo[kc], bhi, acc[nt], 0, 0, 0);
        }
    }

    #pragma unroll
    for (int nt = 0; nt < 4; ++nt) {
        int col = nt * 16 + m;
        #pragma unroll
        for (int r = 0; r < 4; ++r) {
            int row = mbase + quad * 4 + r;
            h_raw[(size_t)row * D_H + col] = acc[nt][r];
        }
    }
}

// Pass 2 (build): unchanged hist/scan/sort; the scale loop now writes hs in
// COLUMN-SLICED layout hs_cs[cg][node][8] (cg = col/8). Values are
// bit-identical to r7: f2bf(h_raw * rsqrtf(count+1)), single rounding.
__global__ __launch_bounds__(256) void build_kernel(const int* __restrict__ cursors,
                                                    const int* __restrict__ region,
                                                    int* __restrict__ offsets,
                                                    float* __restrict__ dinv,
                                                    int* __restrict__ srcs,
                                                    const float* __restrict__ h_raw,
                                                    unsigned short* __restrict__ hs_cs) {
    __shared__ int lhist[NPB];
    __shared__ int lscan[NPB + 1];
    __shared__ int sbuf[256];
    __shared__ int srt[BCAP];
    __shared__ int red[4];
    __shared__ float sdv[NPB];
    int b = blockIdx.x;
    int t = threadIdx.x;

    int c0 = cursors[t];
    int c1 = cursors[t + 256];
    int p = ((t < b) ? c0 : 0) + ((t + 256 < b) ? c1 : 0);
    int lane = t & 63, wid = t >> 6;
    #pragma unroll
    for (int off = 32; off > 0; off >>= 1) p += __shfl_down(p, off);
    if (lane == 0) red[wid] = p;
    __syncthreads();
    int base = red[0] + red[1] + red[2] + red[3];
    int cnt = cursors[b];
    const int* reg = region + b * BCAP;

    for (int i = t; i < NPB; i += 256) lhist[i] = 0;
    __syncthreads();
    for (int i = t; i < cnt; i += 256) {
        int ln = reg[i] >> 17;
        atomicAdd(&lhist[ln], 1);
    }
    __syncthreads();
    int v = (t < NPB) ? lhist[t] : 0;
    sbuf[t] = v;
    __syncthreads();
    for (int off = 1; off < 256; off <<= 1) {
        int u = (t >= off) ? sbuf[t - off] : 0;
        __syncthreads();
        sbuf[t] += u;
        __syncthreads();
    }
    int incl = sbuf[t];
    if (t < NPB) lscan[t] = incl - v;
    if (t == NPB - 1) lscan[NPB] = incl;
    __syncthreads();
    if (t < NPB) lhist[t] = incl - v;
    __syncthreads();

    int node0 = b * NPB;
    int nlim = N_NODES - node0;
    if (nlim > NPB) nlim = NPB;
    if (t < nlim) {
        offsets[node0 + t] = base + lscan[t];
        int c = lscan[t + 1] - lscan[t];
        float dvv = rsqrtf((float)c + 1.0f);
        dinv[node0 + t] = dvv;
        sdv[t] = dvv;
    }
    if (b == (N_NODES - 1) / NPB && t == 0) offsets[N_NODES] = base + cnt;

    for (int i = t; i < cnt; i += 256) {
        int pk = reg[i];
        int ln = pk >> 17;
        int pos = atomicAdd(&lhist[ln], 1);
        srt[pos] = pk & 0x1FFFF;
    }
    __syncthreads();   // also guarantees sdv[] fully written
    for (int i = t; i < cnt; i += 256) srcs[base + i] = srt[i];

    // scale + write col-sliced: thread handles 4 cols (q=0..15 -> c0=4q).
    // reads coalesced float4; writes ushort4 (8B aligned) into slice q>>1.
    int tot = nlim * 16;
    for (int i = t; i < tot; i += 256) {
        int r  = i >> 4;
        int q  = i & 15;
        int cg = q >> 1;
        int sub = (q & 1) * 4;
        int row = node0 + r;
        floatx4 hv = *(const floatx4*)(h_raw + (size_t)row * D_H + cg * 8 + sub);
        float s = sdv[r];
        ushort4 o;
        o.x = f2bf(hv.x * s); o.y = f2bf(hv.y * s);
        o.z = f2bf(hv.z * s); o.w = f2bf(hv.w * s);
        *(ushort4*)(hs_cs + (size_t)cg * HS_SLICE + (size_t)row * 8 + sub) = o;
    }
}

// ---------------------------------------------------------------------------
// agg1a: layer-1 aggregation, COLUMN-SLICED + XCD-PINNED.
// cg = bid&7 == bid%8 == XCD (round-robin dispatch) -> slice cg (1.6 MB)
// becomes resident in that XCD's 4 MB L2; all gathers are L2 hits.
// One THREAD per (node, 8-col slice): plain serial CSR walk, 16B gathers,
// 8 fmacs/edge. Sums are bit-identical to r7's per-column e-order sums.
// Writes raw f32 sums to agg_raw (dv/bias/ReLU/W2 applied in proj_kernel).
// ---------------------------------------------------------------------------
__global__ __launch_bounds__(256) void agg1a_kernel(const unsigned short* __restrict__ hs_cs,
                                                    const int* __restrict__ offsets,
                                                    const int* __restrict__ srcs,
                                                    float* __restrict__ agg_raw) {
    const int cg    = blockIdx.x & 7;
    const int chunk = blockIdx.x >> 3;
    const int node  = chunk * 256 + threadIdx.x;
    if (node >= N_NODES) return;

    const unsigned short* slice = hs_cs + (size_t)cg * HS_SLICE;
    const int beg = offsets[node];
    const int end = offsets[node + 1];

    // self loop
    ushort4 s0 = *(const ushort4*)(slice + (size_t)node * 8);
    ushort4 s1 = *(const ushort4*)(slice + (size_t)node * 8 + 4);
    float a0 = bf2f(s0.x), a1 = bf2f(s0.y), a2 = bf2f(s0.z), a3 = bf2f(s0.w);
    float a4 = bf2f(s1.x), a5 = bf2f(s1.y), a6 = bf2f(s1.z), a7 = bf2f(s1.w);

    for (int e = beg; e < end; ++e) {
        int j = srcs[e];
        ushort4 v0 = *(const ushort4*)(slice + (size_t)j * 8);
        ushort4 v1 = *(const ushort4*)(slice + (size_t)j * 8 + 4);
        a0 += bf2f(v0.x); a1 += bf2f(v0.y); a2 += bf2f(v0.z); a3 += bf2f(v0.w);
        a4 += bf2f(v1.x); a5 += bf2f(v1.y); a6 += bf2f(v1.z); a7 += bf2f(v1.w);
    }

    float* o = agg_raw + (size_t)node * D_H + cg * 8;
    floatx4 w0 = {a0, a1, a2, a3};
    floatx4 w1 = {a4, a5, a6, a7};
    *(floatx4*)(o)     = w0;
    *(floatx4*)(o + 4) = w1;
}

// proj: ReLU + W2 projection (the epilogue that used to live in agg1).
// 16 lanes per node; identical math/order to r7's fused epilogue.
// Writes h2s in COLUMN-SLICED layout h2s_cs[sl>>2][node][sl&3].
__global__ __launch_bounds__(256) void proj_kernel(const float* __restrict__ agg_raw,
                                                   const float* __restrict__ dinv,
                                                   const float* __restrict__ b1,
                                                   const float* __restrict__ W2,
                                                   float* __restrict__ h2s_cs) {
    __shared__ float w2t[16 * 68];
    __shared__ float rbuf[16 * 68];

    const int tid = threadIdx.x;
    for (int i = tid; i < 1024; i += 256) {
        int j = i >> 4, c = i & 15;
        w2t[c * 68 + j] = W2[i];
    }

    const int g    = tid >> 4;
    const int sl   = tid & 15;
    const int node = blockIdx.x * 16 + g;   // 6250*16 == 100000 exact
    const int c4   = sl * 4;

    const float dv = dinv[node];
    floatx4 av = *(const floatx4*)(agg_raw + (size_t)node * D_H + c4);
    const floatx4 bb = *(const floatx4*)(b1 + c4);
    float* rb = rbuf + g * 68;
    rb[c4 + 0] = fmaxf(av.x * dv + bb.x, 0.f);
    rb[c4 + 1] = fmaxf(av.y * dv + bb.y, 0.f);
    rb[c4 + 2] = fmaxf(av.z * dv + bb.z, 0.f);
    rb[c4 + 3] = fmaxf(av.w * dv + bb.w, 0.f);
    __syncthreads();

    float p = 0.f;
    #pragma unroll
    for (int t4 = 0; t4 < 16; ++t4) {
        floatx4 rv = *(const floatx4*)(rb + 4 * t4);
        floatx4 wv = *(const floatx4*)(&w2t[sl * 68 + 4 * t4]);
        p += rv.x * wv.x + rv.y * wv.y + rv.z * wv.z + rv.w * wv.w;
    }
    h2s_cs[(size_t)(sl >> 2) * H2S_SLICE + (size_t)node * 4 + (sl & 3)] = p * dv;
}

// agg2a: layer-2 aggregation, COLUMN-SLICED + XCD-pinned (slice in the two
// XCDs {cg, cg+4}). One thread per (node, 4-col f32 slice); plain CSR walk,
// 16B gathers, 4 fmacs/edge; epilogue *dinv + b2, coalesced 16B out write.
__global__ __launch_bounds__(256) void agg2a_kernel(const float* __restrict__ h2s_cs,
                                                    const int* __restrict__ offsets,
                                                    const int* __restrict__ srcs,
                                                    const float* __restrict__ dinv,
                                                    const float* __restrict__ b2,
                                                    float* __restrict__ out) {
    const int cg    = blockIdx.x & 3;
    const int chunk = blockIdx.x >> 2;
    const int node  = chunk * 256 + threadIdx.x;
    if (node >= N_NODES) return;

    const float* slice = h2s_cs + (size_t)cg * H2S_SLICE;
    const int beg = offsets[node];
    const int end = offsets[node + 1];

    floatx4 acc = *(const floatx4*)(slice + (size_t)node * 4);  // self loop
    for (int e = beg; e < end; ++e) {
        int j = srcs[e];
        floatx4 v = *(const floatx4*)(slice + (size_t)j * 4);
        acc.x += v.x; acc.y += v.y; acc.z += v.z; acc.w += v.w;
    }

    const float dv = dinv[node];
    const floatx4 bb = *(const floatx4*)(b2 + cg * 4);
    floatx4 o;
    o.x = acc.x * dv + bb.x;
    o.y = acc.y * dv + bb.y;
    o.z = acc.z * dv + bb.z;
    o.w = acc.w * dv + bb.w;
    *(floatx4*)(out + (size_t)node * D_OUT + cg * 4) = o;
}

extern "C" void kernel_launch(void* const* d_in, const int* in_sizes, int n_in,
                              void* d_out, int out_size, void* d_ws, size_t ws_size,
                              hipStream_t stream) {
    const float* x  = (const float*)d_in[0];
    const int*   ei = (const int*)d_in[1];
    const float* W1 = (const float*)d_in[2];
    const float* b1 = (const float*)d_in[3];
    const float* W2 = (const float*)d_in[4];
    const float* b2 = (const float*)d_in[5];
    float* out = (float*)d_out;

    const int* src = ei;             // edge_index[0]
    const int* dst = ei + N_EDGES;   // edge_index[1]

    char* w = (char*)d_ws;
    int*   cursors  = (int*)(w + 0);
    int*   offsets  = (int*)(w + 4096);
    float* dinv     = (float*)(w + 404224);
    int*   srcs     = (int*)(w + 804224);
    unsigned short* hs_cs = (unsigned short*)(w + 7204352);
    float* h2s_cs   = (float*)(w + 20004480);
    int*   region   = (int*)(w + 26404480);
    float* h_raw    = (float*)(w + 34793088);
    float* agg_raw  = (float*)(w + 60393088);

    zero_small_kernel<<<1, 512, 0, stream>>>(cursors, srcs);
    fused_bin_gemm1_kernel<<<G1 + GEMM_BLOCKS, 256, 0, stream>>>(
        src, dst, cursors, region, x, W1, h_raw);
    build_kernel<<<NBKT, 256, 0, stream>>>(cursors, region, offsets, dinv, srcs,
                                           h_raw, hs_cs);
    agg1a_kernel<<<8 * NCHUNK, 256, 0, stream>>>(hs_cs, offsets, srcs, agg_raw);
    proj_kernel<<<6250, 256, 0, stream>>>(agg_raw, dinv, b1, W2, h2s_cs);
    agg2a_kernel<<<4 * NCHUNK, 256, 0, stream>>>(h2s_cs, offsets, srcs, dinv, b2, out);
}

// Round 9
// 199.796 us; speedup vs baseline: 1.8130x; 1.8130x over previous
//
#include <hip/hip_runtime.h>
#include <cstdint>

// Problem constants (from reference)
#define N_NODES 100000
#define N_EDGES 1600000
#define D_IN    128
#define D_H     64
#define D_OUT   16
#define M_TILES 6250  // N_NODES / 16

// Bucket sort parameters
#define NBKT   512
#define NPB    196           // nodes per bucket; 512*196 = 100352 >= N
#define BCAP   4096          // per-bucket region capacity (mean 3125, sd 56 -> +17 sigma)
#define TILE_E 4096          // edges per bin tile (256 thr x 16); N_EDGES % 16 == 0
#define NTILES ((N_EDGES + TILE_E - 1) / TILE_E)   // 391
#define G1     391           // bin-phase blocks == NTILES: ONE tile per block
#define GEMM_BLOCKS ((M_TILES + 3) / 4)            // 1563
#define FUSED_LDS 32768      // dynamic LDS: bin uses first 4KB, gemm all 32KB

typedef __attribute__((ext_vector_type(8))) short short8;
typedef __attribute__((ext_vector_type(4))) float floatx4;

// float -> bf16 bits (round to nearest even)
static __device__ __forceinline__ unsigned short f2bf(float f) {
    unsigned int u = __float_as_uint(f);
    u = u + 0x7FFFu + ((u >> 16) & 1u);
    return (unsigned short)(u >> 16);
}
static __device__ __forceinline__ float bf2f(unsigned short h) {
    return __uint_as_float(((unsigned int)h) << 16);
}

// ---------------------------------------------------------------------------
// Workspace layout (bytes, 128-aligned).
//   cursors : NBKT int          @ 0
//   offsets : N+1 int           @ 4096
//   dinv    : N float           @ 404224
//   srcs    : E+16 int (CSR)    @ 804224    (ends 7204288)
//   hs      : N*64 bf16 bits    @ 7204352   (ends 20004352)   [scaled, agg1 input]
//   h2s     : N*16 float        @ 20004480  (ends 26404480)
//   region  : NBKT*BCAP int     @ 26404480  (ends 34793088)
//   h_raw   : N*64 float        @ 34793088  (ends 60393088)   [raw x@W1, f32]
// total ~60.4 MB (workspace is 256 MB)
// ---------------------------------------------------------------------------

__global__ __launch_bounds__(512) void zero_small_kernel(int* __restrict__ cursors,
                                                         int* __restrict__ srcs) {
    cursors[threadIdx.x] = 0;
    if (threadIdx.x < 16) srcs[N_EDGES + threadIdx.x] = 0;  // gather-batch pad
}

// ---------------------------------------------------------------------------
// FUSED prep + transform kernel.
//   blocks [0, G1)          : edge binning — ONE 4096-edge tile per block
//   blocks [G1, G1+GEMM)    : gemm1 via MFMA bf16x2, writes RAW f32 h
// Dynamic LDS union: bin aliases the first 4KB (hcnt/hbase) of the region
// the gemm phase uses for its 32KB W1 staging — branches are block-uniform,
// so the aliasing is safe. 32KB/block -> 5 blocks/CU (was 36KB -> 4).
// gemm1 writes RAW f32 h (no dinv); the scale+bf16 quantization happens in
// build_kernel, keeping stored-hs bit-identical to the r3-proven math.
// ---------------------------------------------------------------------------
__global__ __launch_bounds__(256) void fused_bin_gemm1_kernel(
        const int* __restrict__ src, const int* __restrict__ dst,
        int* __restrict__ cursors, int* __restrict__ region,
        const float* __restrict__ x, const float* __restrict__ W1,
        float* __restrict__ h_raw) {
    extern __shared__ char smem[];
    const int t = threadIdx.x;

    if (blockIdx.x < G1) {
        // ---------------- bin phase (one tile) ----------------
        int* hcnt  = (int*)smem;            // 2048 B
        int* hbase = (int*)(smem + 2048);   // 2048 B
        const int tile = blockIdx.x;        // G1 == NTILES: exactly one tile
        for (int i = t; i < NBKT; i += 256) hcnt[i] = 0;
        __syncthreads();
        int e0 = tile * TILE_E + t * 16;
        int pk[16], bk[16], rk[16];
        bool full = (e0 + 16 <= N_EDGES);   // all-or-nothing: N_EDGES % 16 == 0
        if (full) {
            const int4* dp = (const int4*)(dst + e0);
            const int4* sp = (const int4*)(src + e0);
            int dv[16], sv[16];
            #pragma unroll
            for (int q = 0; q < 4; ++q) {
                int4 d4 = dp[q]; int4 s4 = sp[q];
                dv[4*q+0]=d4.x; dv[4*q+1]=d4.y; dv[4*q+2]=d4.z; dv[4*q+3]=d4.w;
                sv[4*q+0]=s4.x; sv[4*q+1]=s4.y; sv[4*q+2]=s4.z; sv[4*q+3]=s4.w;
            }
            #pragma unroll
            for (int k = 0; k < 16; ++k) {
                int d = dv[k];
                int b = d / NPB;          // const divide -> mul/shift
                bk[k] = b;
                pk[k] = ((d - b * NPB) << 17) | sv[k];
                rk[k] = atomicAdd(&hcnt[b], 1);
            }
        }
        __syncthreads();
        for (int i = t; i < NBKT; i += 256) {
            int c = hcnt[i];
            if (c > 0) hbase[i] = atomicAdd(&cursors[i], c);
        }
        __syncthreads();
        if (full) {
            #pragma unroll
            for (int k = 0; k < 16; ++k)
                region[bk[k] * BCAP + hbase[bk[k]] + rk[k]] = pk[k];
        }
        return;
    }

    // ---------------- gemm1 phase ----------------
    unsigned short* bhi_lds = (unsigned short*)smem;            // 16384 B
    unsigned short* blo_lds = (unsigned short*)(smem + 16384);  // 16384 B
    for (int e = t; e < 8192; e += 256) {
        int j    = e & 7;
        int lane = (e >> 3) & 63;
        int pair = e >> 9;
        int kc   = pair >> 2;
        int nt   = pair & 3;
        int k = kc * 32 + (lane >> 4) * 8 + j;
        int n = nt * 16 + (lane & 15);
        float w = W1[k * D_H + n];
        unsigned short hi = f2bf(w);
        float lo = w - bf2f(hi);
        bhi_lds[e] = hi;
        blo_lds[e] = f2bf(lo);
    }
    __syncthreads();

    int wid  = t >> 6;
    int lane = t & 63;
    int quad = lane >> 4;
    int m    = lane & 15;

    int tile = (blockIdx.x - G1) * 4 + wid;
    if (tile >= M_TILES) return;   // after the only barrier -> safe
    int mbase = tile * 16;

    const float* xr = x + (size_t)(mbase + m) * D_IN + quad * 8;
    short8 ahi[4], alo[4];
    #pragma unroll
    for (int kc = 0; kc < 4; ++kc) {
        floatx4 v0 = *(const floatx4*)(xr + kc * 32);
        floatx4 v1 = *(const floatx4*)(xr + kc * 32 + 4);
        float f[8] = {v0.x, v0.y, v0.z, v0.w, v1.x, v1.y, v1.z, v1.w};
        #pragma unroll
        for (int j = 0; j < 8; ++j) {
            unsigned short hi = f2bf(f[j]);
            float lo = f[j] - bf2f(hi);
            ahi[kc][j] = (short)hi;
            alo[kc][j] = (short)f2bf(lo);
        }
    }

    floatx4 acc[4] = {{0.f,0.f,0.f,0.f},{0.f,0.f,0.f,0.f},{0.f,0.f,0.f,0.f},{0.f,0.f,0.f,0.f}};
    #pragma unroll
    for (int kc = 0; kc < 4; ++kc) {
        #pragma unroll
        for (int nt = 0; nt < 4; ++nt) {
            int fo = ((kc * 4 + nt) * 64 + lane) * 8;
            short8 bhi = *(const short8*)&bhi_lds[fo];
            short8 blo = *(const short8*)&blo_lds[fo];
            acc[nt] = __builtin_amdgcn_mfma_f32_16x16x32_bf16(ahi[kc], bhi, acc[nt], 0, 0, 0);
            acc[nt] = __builtin_amdgcn_mfma_f32_16x16x32_bf16(ahi[kc], blo, acc[nt], 0, 0, 0);
            acc[nt] = __builtin_amdgcn_mfma_f32_16x16x32_bf16(alo[kc], bhi, acc[nt], 0, 0, 0);
        }
    }

    // raw f32 write; dinv scale + bf16 quantization deferred to build_kernel
    #pragma unroll
    for (int nt = 0; nt < 4; ++nt) {
        int col = nt * 16 + m;
        #pragma unroll
        for (int r = 0; r < 4; ++r) {
            int row = mbase + quad * 4 + r;
            h_raw[(size_t)row * D_H + col] = acc[nt][r];
        }
    }
}

// Pass 2: one block per bucket. Computes its own base via masked block
// reduction over the 512 bucket counts. Local hist+scan over 196 nodes ->
// offsets/dinv, sort entries in LDS, write CSR segment SEQUENTIALLY.
// Also applies the dinv scale to this bucket's h_raw rows, producing the
// bf16 hs that agg1 gathers (bit-identical to r3's gemm1 output).
__global__ __launch_bounds__(256) void build_kernel(const int* __restrict__ cursors,
                                                    const int* __restrict__ region,
                                                    int* __restrict__ offsets,
                                                    float* __restrict__ dinv,
                                                    int* __restrict__ srcs,
                                                    const float* __restrict__ h_raw,
                                                    unsigned short* __restrict__ hs) {
    __shared__ int lhist[NPB];        // counts, then running cursors
    __shared__ int lscan[NPB + 1];
    __shared__ int sbuf[256];
    __shared__ int srt[BCAP];
    __shared__ int red[4];
    __shared__ float sdv[NPB];
    int b = blockIdx.x;
    int t = threadIdx.x;

    // base = sum of cursors[i] for i < b  (masked reduction, 512 counts)
    int c0 = cursors[t];
    int c1 = cursors[t + 256];
    int p = ((t < b) ? c0 : 0) + ((t + 256 < b) ? c1 : 0);
    int lane = t & 63, wid = t >> 6;
    #pragma unroll
    for (int off = 32; off > 0; off >>= 1) p += __shfl_down(p, off);
    if (lane == 0) red[wid] = p;
    __syncthreads();
    int base = red[0] + red[1] + red[2] + red[3];
    int cnt = cursors[b];
    const int* reg = region + b * BCAP;

    for (int i = t; i < NPB; i += 256) lhist[i] = 0;
    __syncthreads();
    for (int i = t; i < cnt; i += 256) {
        int ln = reg[i] >> 17;
        atomicAdd(&lhist[ln], 1);
    }
    __syncthreads();
    // exclusive scan of lhist[0..NPB-1]
    int v = (t < NPB) ? lhist[t] : 0;
    sbuf[t] = v;
    __syncthreads();
    for (int off = 1; off < 256; off <<= 1) {
        int u = (t >= off) ? sbuf[t - off] : 0;
        __syncthreads();
        sbuf[t] += u;
        __syncthreads();
    }
    int incl = sbuf[t];
    if (t < NPB) lscan[t] = incl - v;
    if (t == NPB - 1) lscan[NPB] = incl;
    __syncthreads();
    if (t < NPB) lhist[t] = incl - v;   // running cursor = exclusive scan
    __syncthreads();

    // offsets + dinv for this bucket's node range
    int node0 = b * NPB;
    int nlim = N_NODES - node0;
    if (nlim > NPB) nlim = NPB;
    if (t < nlim) {
        offsets[node0 + t] = base + lscan[t];
        int c = lscan[t + 1] - lscan[t];
        float dvv = rsqrtf((float)c + 1.0f);   // +1 self loop
        dinv[node0 + t] = dvv;
        sdv[t] = dvv;
    }
    if (b == (N_NODES - 1) / NPB && t == 0) offsets[N_NODES] = base + cnt;

    // place entries into sorted LDS buffer
    for (int i = t; i < cnt; i += 256) {
        int pk = reg[i];
        int ln = pk >> 17;
        int pos = atomicAdd(&lhist[ln], 1);
        srt[pos] = pk & 0x1FFFF;
    }
    __syncthreads();   // also guarantees sdv[] fully written
    // sequential write-out (coalesced full lines)
    for (int i = t; i < cnt; i += 256) srcs[base + i] = srt[i];

    // scale this bucket's h rows: hs = f2bf(h_raw * dinv)  (single rounding,
    // identical to r3's in-gemm scale). Coalesced: 196*64 f32 reads/block.
    int tot = nlim * D_H;
    for (int i = t; i < tot; i += 256) {
        int r = i >> 6;            // 0..nlim-1
        int c = i & 63;
        size_t off = (size_t)(node0 + r) * D_H + c;
        hs[off] = f2bf(h_raw[off] * sdv[r]);
    }
}

// Fused layer-1 aggregation + ReLU + layer-2 linear (r3-proven version).
// 16 lanes per node, 4 bf16 columns per lane. Per batch of 16 edges: one
// coalesced per-lane index load (64B/group), then 16 steps of {__shfl
// broadcast within 16-lane group -> 8B gather -> 4 masked fmacs}. hs rows
// are PRE-SCALED by dinv[src], so the inner loop has no per-edge weight
// traffic. Projection via padded LDS transpose.
// NOTE (r8 lesson): this kernel is AT its compulsory-traffic floor
// (~90 MB = 8 XCDs x 86.5K expected-distinct 128B rows) at the ~2.3-2.5 TB/s
// random-line L2-miss service rate. Do not restructure further.
__global__ __launch_bounds__(256) void agg1_fused_kernel(const unsigned short* __restrict__ hs,
                                                         const int* __restrict__ offsets,
                                                         const int* __restrict__ srcs,
                                                         const float* __restrict__ dinv,
                                                         const float* __restrict__ b1,
                                                         const float* __restrict__ W2,
                                                         float* __restrict__ h2s) {
    __shared__ float w2t[16 * 68];   // w2t[c*68 + j] = W2[j*16 + c]
    __shared__ float rbuf[16 * 68];  // per group: 68-float stride (64 used)

    const int tid = threadIdx.x;
    // stage W2 transposed (once per block)
    for (int i = tid; i < 1024; i += 256) {
        int j = i >> 4, c = i & 15;
        w2t[c * 68 + j] = W2[i];
    }

    const int g    = tid >> 4;              // group within block, 0..15
    const int sl   = tid & 15;              // sublane within group
    const int node = blockIdx.x * 16 + g;   // 6250*16 == 100000 exact
    const int c4   = sl * 4;                // column base (of 64)

    const int beg = offsets[node];
    const int end = offsets[node + 1];

    // self-loop init: 4 bf16 cols of own (pre-scaled) row
    ushort4 s4v = *(const ushort4*)(hs + (size_t)node * D_H + c4);
    float a0 = bf2f(s4v.x), a1 = bf2f(s4v.y), a2 = bf2f(s4v.z), a3 = bf2f(s4v.w);

    for (int e = beg; e < end; e += 16) {
        int rem = end - e;
        int idx = srcs[e + sl];            // coalesced 64B per group; pad-safe
        #pragma unroll
        for (int k = 0; k < 16; ++k) {
            int j = __shfl(idx, k, 16);    // broadcast within 16-lane group
            ushort4 v = *(const ushort4*)(hs + (size_t)j * D_H + c4);
            float m = (k < rem) ? 1.0f : 0.0f;
            a0 = fmaf(bf2f(v.x), m, a0);
            a1 = fmaf(bf2f(v.y), m, a1);
            a2 = fmaf(bf2f(v.z), m, a2);
            a3 = fmaf(bf2f(v.w), m, a3);
        }
    }

    const float dv = dinv[node];
    const floatx4 bb = *(const floatx4*)(b1 + c4);
    float* rb = rbuf + g * 68;
    rb[c4 + 0] = fmaxf(a0 * dv + bb.x, 0.f);
    rb[c4 + 1] = fmaxf(a1 * dv + bb.y, 0.f);
    rb[c4 + 2] = fmaxf(a2 * dv + bb.z, 0.f);
    rb[c4 + 3] = fmaxf(a3 * dv + bb.w, 0.f);
    __syncthreads();   // single pass per thread -> block-wide barrier is safe

    // out[node][sl] = sum_j r[j] * W2[j][sl]   (then * dv)
    float p = 0.f;
    #pragma unroll
    for (int t4 = 0; t4 < 16; ++t4) {
        floatx4 rv = *(const floatx4*)(rb + 4 * t4);
        floatx4 wv = *(const floatx4*)(&w2t[sl * 68 + 4 * t4]);
        p += rv.x * wv.x + rv.y * wv.y + rv.z * wv.z + rv.w * wv.w;
    }
    h2s[node * D_OUT + sl] = p * dv;
}

// out[i][c] = dinv[i]*(h2s[i][c] + sum_{j->i} h2s[j][c]) + b2[c]
// 16 threads per node; padded srcs (no clamp), fmac-masked 16-wide batches.
__global__ __launch_bounds__(256) void agg2_kernel(const float* __restrict__ h2s,
                                                   const int* __restrict__ offsets,
                                                   const int* __restrict__ srcs,
                                                   const float* __restrict__ dinv,
                                                   const float* __restrict__ b2,
                                                   float* __restrict__ out) {
    int col = threadIdx.x & 15;
    int nidx = (blockIdx.x * blockDim.x + threadIdx.x) >> 4;
    int stride = (gridDim.x * blockDim.x) >> 4;
    for (int node = nidx; node < N_NODES; node += stride) {
        int beg = offsets[node], end = offsets[node + 1];
        float acc = h2s[node * D_OUT + col];  // self loop
        for (int e = beg; e < end; e += 16) {
            int rem = end - e;
            const int* ep = srcs + e;
            int jj[16];
            #pragma unroll
            for (int k = 0; k < 16; ++k) jj[k] = ep[k];
            float vv[16];
            #pragma unroll
            for (int k = 0; k < 16; ++k) vv[k] = h2s[jj[k] * D_OUT + col];
            #pragma unroll
            for (int k = 0; k < 16; ++k) {
                float m = (k < rem) ? 1.0f : 0.0f;
                acc = fmaf(vv[k], m, acc);
            }
        }
        out[node * D_OUT + col] = acc * dinv[node] + b2[col];
    }
}

extern "C" void kernel_launch(void* const* d_in, const int* in_sizes, int n_in,
                              void* d_out, int out_size, void* d_ws, size_t ws_size,
                              hipStream_t stream) {
    const float* x  = (const float*)d_in[0];
    const int*   ei = (const int*)d_in[1];
    const float* W1 = (const float*)d_in[2];
    const float* b1 = (const float*)d_in[3];
    const float* W2 = (const float*)d_in[4];
    const float* b2 = (const float*)d_in[5];
    float* out = (float*)d_out;

    const int* src = ei;             // edge_index[0]
    const int* dst = ei + N_EDGES;   // edge_index[1]

    char* w = (char*)d_ws;
    int*   cursors  = (int*)(w + 0);
    int*   offsets  = (int*)(w + 4096);
    float* dinv     = (float*)(w + 404224);
    int*   srcs     = (int*)(w + 804224);
    unsigned short* hs = (unsigned short*)(w + 7204352);
    float* h2s      = (float*)(w + 20004480);
    int*   region   = (int*)(w + 26404480);
    float* h_raw    = (float*)(w + 34793088);

    zero_small_kernel<<<1, 512, 0, stream>>>(cursors, srcs);
    fused_bin_gemm1_kernel<<<G1 + GEMM_BLOCKS, 256, FUSED_LDS, stream>>>(
        src, dst, cursors, region, x, W1, h_raw);
    build_kernel<<<NBKT, 256, 0, stream>>>(cursors, region, offsets, dinv, srcs,
                                           h_raw, hs);
    agg1_fused_kernel<<<6250, 256, 0, stream>>>(hs, offsets, srcs, dinv, b1, W2, h2s);
    agg2_kernel<<<6250, 256, 0, stream>>>(h2s, offsets, srcs, dinv, b2, out);
}

// Round 11
// 195.800 us; speedup vs baseline: 1.8500x; 1.0204x over previous
//
#include <hip/hip_runtime.h>
#include <cstdint>

// Problem constants (from reference)
#define N_NODES 100000
#define N_EDGES 1600000
#define D_IN    128
#define D_H     64
#define D_OUT   16
#define M_TILES 6250  // N_NODES / 16

// Bucket sort parameters
#define NBKT   512
#define NPB    196           // nodes per bucket; 512*196 = 100352 >= N
#define BCAP   4096          // per-bucket region capacity (mean 3125, sd 56 -> +17 sigma)
#define TILE_E 4096          // edges per bin tile (256 thr x 16); N_EDGES % 16 == 0
#define NTILES ((N_EDGES + TILE_E - 1) / TILE_E)   // 391 bin tiles
#define GEMM_BLOCKS ((M_TILES + 7) / 8)            // 782: 8 tiles/block, 2/wave
#define FUSED_T (GEMM_BLOCKS + NTILES)             // 1173 total fused blocks
#define FUSED_LDS 32768      // dynamic LDS: bin uses first 4KB, gemm all 32KB

typedef __attribute__((ext_vector_type(8))) short short8;
typedef __attribute__((ext_vector_type(4))) float floatx4;

// float -> bf16 bits (round to nearest even)
static __device__ __forceinline__ unsigned short f2bf(float f) {
    unsigned int u = __float_as_uint(f);
    u = u + 0x7FFFu + ((u >> 16) & 1u);
    return (unsigned short)(u >> 16);
}
static __device__ __forceinline__ float bf2f(unsigned short h) {
    return __uint_as_float(((unsigned int)h) << 16);
}

// ---------------------------------------------------------------------------
// Workspace layout (bytes, 128-aligned).
//   cursors : NBKT int          @ 0
//   offsets : N+1 int           @ 4096
//   dinv    : N float           @ 404224
//   srcs    : E+16 int (CSR)    @ 804224    (ends 7204288)
//   hs      : N*64 bf16 bits    @ 7204352   (ends 20004352)   [scaled, agg1 input]
//   h2s     : N*16 float        @ 20004480  (ends 26404480)
//   region  : NBKT*BCAP int     @ 26404480  (ends 34793088)
//   h_raw   : N*64 float        @ 34793088  (ends 60393088)   [raw x@W1, f32]
// total ~60.4 MB (workspace is 256 MB)
// ---------------------------------------------------------------------------

__global__ __launch_bounds__(512) void zero_small_kernel(int* __restrict__ cursors,
                                                         int* __restrict__ srcs) {
    cursors[threadIdx.x] = 0;
    if (threadIdx.x < 16) srcs[N_EDGES + threadIdx.x] = 0;  // gather-batch pad
}

// ---------------------------------------------------------------------------
// FUSED prep + transform kernel, INTERLEAVED block mapping:
//   bid % 3 == 0  (391 blocks, bid/3 = tile)   : edge binning, one tile each
//   otherwise     (782 blocks)                 : gemm1, 8 tiles/block, 2/wave
// gemm waves issue BOTH tiles' x loads up front (16 indep loads in flight;
// tile-A MFMA covers tile-B load latency) — attacks the wave-level serial
// load->convert->MFMA chain that r9's occupancy knobs couldn't move.
// Dynamic LDS union: bin aliases first 4KB of gemm's 32KB W1 staging
// (block-uniform branch -> safe). gemm writes RAW f32 h; scale+quantization
// happen in build_kernel (bit-identical to r3-proven math).
// ---------------------------------------------------------------------------
__global__ __launch_bounds__(256) void fused_bin_gemm1_kernel(
        const int* __restrict__ src, const int* __restrict__ dst,
        int* __restrict__ cursors, int* __restrict__ region,
        const float* __restrict__ x, const float* __restrict__ W1,
        float* __restrict__ h_raw) {
    extern __shared__ char smem[];
    const int t   = threadIdx.x;
    const int bid = blockIdx.x;

    if (bid % 3 == 0) {
        // ---------------- bin phase (one tile) ----------------
        int* hcnt  = (int*)smem;            // 2048 B
        int* hbase = (int*)(smem + 2048);   // 2048 B
        const int tile = bid / 3;           // 0..390
        for (int i = t; i < NBKT; i += 256) hcnt[i] = 0;
        __syncthreads();
        int e0 = tile * TILE_E + t * 16;
        int pk[16], bk[16], rk[16];
        bool full = (e0 + 16 <= N_EDGES);   // all-or-nothing: N_EDGES % 16 == 0
        if (full) {
            const int4* dp = (const int4*)(dst + e0);
            const int4* sp = (const int4*)(src + e0);
            int dv[16], sv[16];
            #pragma unroll
            for (int q = 0; q < 4; ++q) {
                int4 d4 = dp[q]; int4 s4 = sp[q];
                dv[4*q+0]=d4.x; dv[4*q+1]=d4.y; dv[4*q+2]=d4.z; dv[4*q+3]=d4.w;
                sv[4*q+0]=s4.x; sv[4*q+1]=s4.y; sv[4*q+2]=s4.z; sv[4*q+3]=s4.w;
            }
            #pragma unroll
            for (int k = 0; k < 16; ++k) {
                int d = dv[k];
                int b = d / NPB;          // const divide -> mul/shift
                bk[k] = b;
                pk[k] = ((d - b * NPB) << 17) | sv[k];
                rk[k] = atomicAdd(&hcnt[b], 1);
            }
        }
        __syncthreads();
        for (int i = t; i < NBKT; i += 256) {
            int c = hcnt[i];
            if (c > 0) hbase[i] = atomicAdd(&cursors[i], c);
        }
        __syncthreads();
        if (full) {
            #pragma unroll
            for (int k = 0; k < 16; ++k)
                region[bk[k] * BCAP + hbase[bk[k]] + rk[k]] = pk[k];
        }
        return;
    }

    // ---------------- gemm1 phase ----------------
    unsigned short* bhi_lds = (unsigned short*)smem;            // 16384 B
    unsigned short* blo_lds = (unsigned short*)(smem + 16384);  // 16384 B
    for (int e = t; e < 8192; e += 256) {
        int j    = e & 7;
        int lane = (e >> 3) & 63;
        int pair = e >> 9;
        int kc   = pair >> 2;
        int nt   = pair & 3;
        int k = kc * 32 + (lane >> 4) * 8 + j;
        int n = nt * 16 + (lane & 15);
        float w = W1[k * D_H + n];
        unsigned short hi = f2bf(w);
        float lo = w - bf2f(hi);
        bhi_lds[e] = hi;
        blo_lds[e] = f2bf(lo);
    }
    __syncthreads();

    const int gidx = bid - bid / 3 - 1;   // bijection onto 0..781
    const int wid  = t >> 6;
    const int lane = t & 63;
    const int quad = lane >> 4;
    const int m    = lane & 15;

    const int tA = gidx * 8 + wid;        // wave's two tiles: tA and tA+4
    const int tB = tA + 4;
    const bool vA = (tA < M_TILES);
    const bool vB = (tB < M_TILES);

    // issue BOTH tiles' x loads before any compute (16 independent loads)
    floatx4 xA[8], xB[8];
    if (vA) {
        const float* xr = x + (size_t)(tA * 16 + m) * D_IN + quad * 8;
        #pragma unroll
        for (int kc = 0; kc < 4; ++kc) {
            xA[2*kc]   = *(const floatx4*)(xr + kc * 32);
            xA[2*kc+1] = *(const floatx4*)(xr + kc * 32 + 4);
        }
    }
    if (vB) {
        const float* xr = x + (size_t)(tB * 16 + m) * D_IN + quad * 8;
        #pragma unroll
        for (int kc = 0; kc < 4; ++kc) {
            xB[2*kc]   = *(const floatx4*)(xr + kc * 32);
            xB[2*kc+1] = *(const floatx4*)(xr + kc * 32 + 4);
        }
    }

    #pragma unroll
    for (int half = 0; half < 2; ++half) {
        const bool valid = half ? vB : vA;
        if (!valid) continue;
        const int tile = half ? tB : tA;
        const floatx4* xs = half ? xB : xA;
        const int mbase = tile * 16;

        short8 ahi[4], alo[4];
        #pragma unroll
        for (int kc = 0; kc < 4; ++kc) {
            floatx4 v0 = xs[2*kc], v1 = xs[2*kc+1];
            float f[8] = {v0.x, v0.y, v0.z, v0.w, v1.x, v1.y, v1.z, v1.w};
            #pragma unroll
            for (int j = 0; j < 8; ++j) {
                unsigned short hi = f2bf(f[j]);
                float lo = f[j] - bf2f(hi);
                ahi[kc][j] = (short)hi;
                alo[kc][j] = (short)f2bf(lo);
            }
        }

        floatx4 acc[4] = {{0.f,0.f,0.f,0.f},{0.f,0.f,0.f,0.f},{0.f,0.f,0.f,0.f},{0.f,0.f,0.f,0.f}};
        #pragma unroll
        for (int kc = 0; kc < 4; ++kc) {
            #pragma unroll
            for (int nt = 0; nt < 4; ++nt) {
                int fo = ((kc * 4 + nt) * 64 + lane) * 8;
                short8 bhi = *(const short8*)&bhi_lds[fo];
                short8 blo = *(const short8*)&blo_lds[fo];
                acc[nt] = __builtin_amdgcn_mfma_f32_16x16x32_bf16(ahi[kc], bhi, acc[nt], 0, 0, 0);
                acc[nt] = __builtin_amdgcn_mfma_f32_16x16x32_bf16(ahi[kc], blo, acc[nt], 0, 0, 0);
                acc[nt] = __builtin_amdgcn_mfma_f32_16x16x32_bf16(alo[kc], bhi, acc[nt], 0, 0, 0);
            }
        }

        // raw f32 write; dinv scale + bf16 quantization deferred to build
        #pragma unroll
        for (int nt = 0; nt < 4; ++nt) {
            int col = nt * 16 + m;
            #pragma unroll
            for (int r = 0; r < 4; ++r) {
                int row = mbase + quad * 4 + r;
                h_raw[(size_t)row * D_H + col] = acc[nt][r];
            }
        }
    }
}

// Pass 2: one block per bucket. Computes its own base via masked block
// reduction over the 512 bucket counts. Local hist+scan over 196 nodes ->
// offsets/dinv, sort entries in LDS, write CSR segment SEQUENTIALLY.
// Also applies the dinv scale to this bucket's h_raw rows, producing the
// bf16 hs that agg1 gathers (bit-identical to r3's gemm1 output).
__global__ __launch_bounds__(256) void build_kernel(const int* __restrict__ cursors,
                                                    const int* __restrict__ region,
                                                    int* __restrict__ offsets,
                                                    float* __restrict__ dinv,
                                                    int* __restrict__ srcs,
                                                    const float* __restrict__ h_raw,
                                                    unsigned short* __restrict__ hs) {
    __shared__ int lhist[NPB];        // counts, then running cursors
    __shared__ int lscan[NPB + 1];
    __shared__ int sbuf[256];
    __shared__ int srt[BCAP];
    __shared__ int red[4];
    __shared__ float sdv[NPB];
    int b = blockIdx.x;
    int t = threadIdx.x;

    // base = sum of cursors[i] for i < b  (masked reduction, 512 counts)
    int c0 = cursors[t];
    int c1 = cursors[t + 256];
    int p = ((t < b) ? c0 : 0) + ((t + 256 < b) ? c1 : 0);
    int lane = t & 63, wid = t >> 6;
    #pragma unroll
    for (int off = 32; off > 0; off >>= 1) p += __shfl_down(p, off);
    if (lane == 0) red[wid] = p;
    __syncthreads();
    int base = red[0] + red[1] + red[2] + red[3];
    int cnt = cursors[b];
    const int* reg = region + b * BCAP;

    for (int i = t; i < NPB; i += 256) lhist[i] = 0;
    __syncthreads();
    for (int i = t; i < cnt; i += 256) {
        int ln = reg[i] >> 17;
        atomicAdd(&lhist[ln], 1);
    }
    __syncthreads();
    // exclusive scan of lhist[0..NPB-1]
    int v = (t < NPB) ? lhist[t] : 0;
    sbuf[t] = v;
    __syncthreads();
    for (int off = 1; off < 256; off <<= 1) {
        int u = (t >= off) ? sbuf[t - off] : 0;
        __syncthreads();
        sbuf[t] += u;
        __syncthreads();
    }
    int incl = sbuf[t];
    if (t < NPB) lscan[t] = incl - v;
    if (t == NPB - 1) lscan[NPB] = incl;
    __syncthreads();
    if (t < NPB) lhist[t] = incl - v;   // running cursor = exclusive scan
    __syncthreads();

    // offsets + dinv for this bucket's node range
    int node0 = b * NPB;
    int nlim = N_NODES - node0;
    if (nlim > NPB) nlim = NPB;
    if (t < nlim) {
        offsets[node0 + t] = base + lscan[t];
        int c = lscan[t + 1] - lscan[t];
        float dvv = rsqrtf((float)c + 1.0f);   // +1 self loop
        dinv[node0 + t] = dvv;
        sdv[t] = dvv;
    }
    if (b == (N_NODES - 1) / NPB && t == 0) offsets[N_NODES] = base + cnt;

    // place entries into sorted LDS buffer
    for (int i = t; i < cnt; i += 256) {
        int pk = reg[i];
        int ln = pk >> 17;
        int pos = atomicAdd(&lhist[ln], 1);
        srt[pos] = pk & 0x1FFFF;
    }
    __syncthreads();   // also guarantees sdv[] fully written
    // sequential write-out (coalesced full lines)
    for (int i = t; i < cnt; i += 256) srcs[base + i] = srt[i];

    // scale this bucket's h rows: hs = f2bf(h_raw * dinv)  (single rounding,
    // identical to r3's in-gemm scale). Coalesced: 196*64 f32 reads/block.
    int tot = nlim * D_H;
    for (int i = t; i < tot; i += 256) {
        int r = i >> 6;            // 0..nlim-1
        int c = i & 63;
        size_t off = (size_t)(node0 + r) * D_H + c;
        hs[off] = f2bf(h_raw[off] * sdv[r]);
    }
}

// Fused layer-1 aggregation + ReLU + layer-2 linear (r3-proven version).
// 16 lanes per node, 4 bf16 columns per lane. Per batch of 16 edges: one
// coalesced per-lane index load (64B/group), then 16 steps of {__shfl
// broadcast within 16-lane group -> 8B gather -> 4 masked fmacs}. hs rows
// are PRE-SCALED by dinv[src], so the inner loop has no per-edge weight
// traffic. Projection via padded LDS transpose.
// NOTE (r8 lesson): this kernel is AT its compulsory-traffic floor
// (~90 MB = 8 XCDs x 86.5K expected-distinct 128B rows) at the ~2.3-2.5 TB/s
// random-line L2-miss service rate. Do not restructure further.
__global__ __launch_bounds__(256) void agg1_fused_kernel(const unsigned short* __restrict__ hs,
                                                         const int* __restrict__ offsets,
                                                         const int* __restrict__ srcs,
                                                         const float* __restrict__ dinv,
                                                         const float* __restrict__ b1,
                                                         const float* __restrict__ W2,
                                                         float* __restrict__ h2s) {
    __shared__ float w2t[16 * 68];   // w2t[c*68 + j] = W2[j*16 + c]
    __shared__ float rbuf[16 * 68];  // per group: 68-float stride (64 used)

    const int tid = threadIdx.x;
    // stage W2 transposed (once per block)
    for (int i = tid; i < 1024; i += 256) {
        int j = i >> 4, c = i & 15;
        w2t[c * 68 + j] = W2[i];
    }

    const int g    = tid >> 4;              // group within block, 0..15
    const int sl   = tid & 15;              // sublane within group
    const int node = blockIdx.x * 16 + g;   // 6250*16 == 100000 exact
    const int c4   = sl * 4;                // column base (of 64)

    const int beg = offsets[node];
    const int end = offsets[node + 1];

    // self-loop init: 4 bf16 cols of own (pre-scaled) row
    ushort4 s4v = *(const ushort4*)(hs + (size_t)node * D_H + c4);
    float a0 = bf2f(s4v.x), a1 = bf2f(s4v.y), a2 = bf2f(s4v.z), a3 = bf2f(s4v.w);

    for (int e = beg; e < end; e += 16) {
        int rem = end - e;
        int idx = srcs[e + sl];            // coalesced 64B per group; pad-safe
        #pragma unroll
        for (int k = 0; k < 16; ++k) {
            int j = __shfl(idx, k, 16);    // broadcast within 16-lane group
            ushort4 v = *(const ushort4*)(hs + (size_t)j * D_H + c4);
            float m = (k < rem) ? 1.0f : 0.0f;
            a0 = fmaf(bf2f(v.x), m, a0);
            a1 = fmaf(bf2f(v.y), m, a1);
            a2 = fmaf(bf2f(v.z), m, a2);
            a3 = fmaf(bf2f(v.w), m, a3);
        }
    }

    const float dv = dinv[node];
    const floatx4 bb = *(const floatx4*)(b1 + c4);
    float* rb = rbuf + g * 68;
    rb[c4 + 0] = fmaxf(a0 * dv + bb.x, 0.f);
    rb[c4 + 1] = fmaxf(a1 * dv + bb.y, 0.f);
    rb[c4 + 2] = fmaxf(a2 * dv + bb.z, 0.f);
    rb[c4 + 3] = fmaxf(a3 * dv + bb.w, 0.f);
    __syncthreads();   // single pass per thread -> block-wide barrier is safe

    // out[node][sl] = sum_j r[j] * W2[j][sl]   (then * dv)
    float p = 0.f;
    #pragma unroll
    for (int t4 = 0; t4 < 16; ++t4) {
        floatx4 rv = *(const floatx4*)(rb + 4 * t4);
        floatx4 wv = *(const floatx4*)(&w2t[sl * 68 + 4 * t4]);
        p += rv.x * wv.x + rv.y * wv.y + rv.z * wv.z + rv.w * wv.w;
    }
    h2s[node * D_OUT + sl] = p * dv;
}

// out[i][c] = dinv[i]*(h2s[i][c] + sum_{j->i} h2s[j][c]) + b2[c]
// 16 threads per node; padded srcs (no clamp), fmac-masked 16-wide batches.
__global__ __launch_bounds__(256) void agg2_kernel(const float* __restrict__ h2s,
                                                   const int* __restrict__ offsets,
                                                   const int* __restrict__ srcs,
                                                   const float* __restrict__ dinv,
                                                   const float* __restrict__ b2,
                                                   float* __restrict__ out) {
    int col = threadIdx.x & 15;
    int nidx = (blockIdx.x * blockDim.x + threadIdx.x) >> 4;
    int stride = (gridDim.x * blockDim.x) >> 4;
    for (int node = nidx; node < N_NODES; node += stride) {
        int beg = offsets[node], end = offsets[node + 1];
        float acc = h2s[node * D_OUT + col];  // self loop
        for (int e = beg; e < end; e += 16) {
            int rem = end - e;
            const int* ep = srcs + e;
            int jj[16];
            #pragma unroll
            for (int k = 0; k < 16; ++k) jj[k] = ep[k];
            float vv[16];
            #pragma unroll
            for (int k = 0; k < 16; ++k) vv[k] = h2s[jj[k] * D_OUT + col];
            #pragma unroll
            for (int k = 0; k < 16; ++k) {
                float m = (k < rem) ? 1.0f : 0.0f;
                acc = fmaf(vv[k], m, acc);
            }
        }
        out[node * D_OUT + col] = acc * dinv[node] + b2[col];
    }
}

extern "C" void kernel_launch(void* const* d_in, const int* in_sizes, int n_in,
                              void* d_out, int out_size, void* d_ws, size_t ws_size,
                              hipStream_t stream) {
    const float* x  = (const float*)d_in[0];
    const int*   ei = (const int*)d_in[1];
    const float* W1 = (const float*)d_in[2];
    const float* b1 = (const float*)d_in[3];
    const float* W2 = (const float*)d_in[4];
    const float* b2 = (const float*)d_in[5];
    float* out = (float*)d_out;

    const int* src = ei;             // edge_index[0]
    const int* dst = ei + N_EDGES;   // edge_index[1]

    char* w = (char*)d_ws;
    int*   cursors  = (int*)(w + 0);
    int*   offsets  = (int*)(w + 4096);
    float* dinv     = (float*)(w + 404224);
    int*   srcs     = (int*)(w + 804224);
    unsigned short* hs = (unsigned short*)(w + 7204352);
    float* h2s      = (float*)(w + 20004480);
    int*   region   = (int*)(w + 26404480);
    float* h_raw    = (float*)(w + 34793088);

    zero_small_kernel<<<1, 512, 0, stream>>>(cursors, srcs);
    fused_bin_gemm1_kernel<<<FUSED_T, 256, FUSED_LDS, stream>>>(
        src, dst, cursors, region, x, W1, h_raw);
    build_kernel<<<NBKT, 256, 0, stream>>>(cursors, region, offsets, dinv, srcs,
                                           h_raw, hs);
    agg1_fused_kernel<<<6250, 256, 0, stream>>>(hs, offsets, srcs, dinv, b1, W2, h2s);
    agg2_kernel<<<6250, 256, 0, stream>>>(h2s, offsets, srcs, dinv, b2, out);
}

// Round 12
// 193.682 us; speedup vs baseline: 1.8702x; 1.0109x over previous
//
#include <hip/hip_runtime.h>
#include <cstdint>

// Problem constants (from reference)
#define N_NODES 100000
#define N_EDGES 1600000
#define D_IN    128
#define D_H     64
#define D_OUT   16
#define M_TILES 6250  // N_NODES / 16

// Bucket sort parameters
#define NBKT   512
#define NPB    196           // nodes per bucket; 512*196 = 100352 >= N
#define BCAP   4096          // per-bucket region capacity (mean 3125, sd 56 -> +17 sigma)
#define TILE_E 4096          // edges per bin tile (256 thr x 16); N_EDGES % 16 == 0
#define NTILES ((N_EDGES + TILE_E - 1) / TILE_E)   // 391 bin tiles
#define GEMM_BLOCKS ((M_TILES + 7) / 8)            // 782: 8 tiles/block, 2/wave
#define FUSED_T (GEMM_BLOCKS + NTILES)             // 1173 total fused blocks
#define FUSED_LDS 32768      // dynamic LDS: bin uses first 4KB, gemm all 32KB

typedef __attribute__((ext_vector_type(8))) short short8;
typedef __attribute__((ext_vector_type(4))) float floatx4;

// float -> bf16 bits (round to nearest even)
static __device__ __forceinline__ unsigned short f2bf(float f) {
    unsigned int u = __float_as_uint(f);
    u = u + 0x7FFFu + ((u >> 16) & 1u);
    return (unsigned short)(u >> 16);
}
static __device__ __forceinline__ float bf2f(unsigned short h) {
    return __uint_as_float(((unsigned int)h) << 16);
}

// ---------------------------------------------------------------------------
// Workspace layout (bytes, 128-aligned).
//   cursors : NBKT int          @ 0
//   offsets : N+1 int           @ 4096
//   dinv    : N float           @ 404224
//   srcs    : E+16 int (CSR)    @ 804224    (ends 7204288)
//   hs      : N*64 bf16 bits    @ 7204352   (ends 20004352)   [scaled, agg1 input]
//   h2s     : N*16 bf16 bits    @ 20004480  (ends 23204480)   [bf16: halves agg2's
//                                                              compulsory line traffic]
//   region  : NBKT*BCAP int     @ 26404480  (ends 34793088)
//   h_raw   : N*64 float        @ 34793088  (ends 60393088)   [raw x@W1, f32]
// total ~60.4 MB (workspace is 256 MB)
// ---------------------------------------------------------------------------

__global__ __launch_bounds__(512) void zero_small_kernel(int* __restrict__ cursors,
                                                         int* __restrict__ srcs) {
    cursors[threadIdx.x] = 0;
    if (threadIdx.x < 16) srcs[N_EDGES + threadIdx.x] = 0;  // gather-batch pad
}

// ---------------------------------------------------------------------------
// FUSED prep + transform kernel, INTERLEAVED block mapping (r11-proven):
//   bid % 3 == 0  (391 blocks, bid/3 = tile)   : edge binning, one tile each
//   otherwise     (782 blocks)                 : gemm1, 8 tiles/block, 2/wave
// ---------------------------------------------------------------------------
__global__ __launch_bounds__(256) void fused_bin_gemm1_kernel(
        const int* __restrict__ src, const int* __restrict__ dst,
        int* __restrict__ cursors, int* __restrict__ region,
        const float* __restrict__ x, const float* __restrict__ W1,
        float* __restrict__ h_raw) {
    extern __shared__ char smem[];
    const int t   = threadIdx.x;
    const int bid = blockIdx.x;

    if (bid % 3 == 0) {
        // ---------------- bin phase (one tile) ----------------
        int* hcnt  = (int*)smem;            // 2048 B
        int* hbase = (int*)(smem + 2048);   // 2048 B
        const int tile = bid / 3;           // 0..390
        for (int i = t; i < NBKT; i += 256) hcnt[i] = 0;
        __syncthreads();
        int e0 = tile * TILE_E + t * 16;
        int pk[16], bk[16], rk[16];
        bool full = (e0 + 16 <= N_EDGES);   // all-or-nothing: N_EDGES % 16 == 0
        if (full) {
            const int4* dp = (const int4*)(dst + e0);
            const int4* sp = (const int4*)(src + e0);
            int dv[16], sv[16];
            #pragma unroll
            for (int q = 0; q < 4; ++q) {
                int4 d4 = dp[q]; int4 s4 = sp[q];
                dv[4*q+0]=d4.x; dv[4*q+1]=d4.y; dv[4*q+2]=d4.z; dv[4*q+3]=d4.w;
                sv[4*q+0]=s4.x; sv[4*q+1]=s4.y; sv[4*q+2]=s4.z; sv[4*q+3]=s4.w;
            }
            #pragma unroll
            for (int k = 0; k < 16; ++k) {
                int d = dv[k];
                int b = d / NPB;          // const divide -> mul/shift
                bk[k] = b;
                pk[k] = ((d - b * NPB) << 17) | sv[k];
                rk[k] = atomicAdd(&hcnt[b], 1);
            }
        }
        __syncthreads();
        for (int i = t; i < NBKT; i += 256) {
            int c = hcnt[i];
            if (c > 0) hbase[i] = atomicAdd(&cursors[i], c);
        }
        __syncthreads();
        if (full) {
            #pragma unroll
            for (int k = 0; k < 16; ++k)
                region[bk[k] * BCAP + hbase[bk[k]] + rk[k]] = pk[k];
        }
        return;
    }

    // ---------------- gemm1 phase ----------------
    unsigned short* bhi_lds = (unsigned short*)smem;            // 16384 B
    unsigned short* blo_lds = (unsigned short*)(smem + 16384);  // 16384 B
    for (int e = t; e < 8192; e += 256) {
        int j    = e & 7;
        int lane = (e >> 3) & 63;
        int pair = e >> 9;
        int kc   = pair >> 2;
        int nt   = pair & 3;
        int k = kc * 32 + (lane >> 4) * 8 + j;
        int n = nt * 16 + (lane & 15);
        float w = W1[k * D_H + n];
        unsigned short hi = f2bf(w);
        float lo = w - bf2f(hi);
        bhi_lds[e] = hi;
        blo_lds[e] = f2bf(lo);
    }
    __syncthreads();

    const int gidx = bid - bid / 3 - 1;   // bijection onto 0..781
    const int wid  = t >> 6;
    const int lane = t & 63;
    const int quad = lane >> 4;
    const int m    = lane & 15;

    const int tA = gidx * 8 + wid;        // wave's two tiles: tA and tA+4
    const int tB = tA + 4;
    const bool vA = (tA < M_TILES);
    const bool vB = (tB < M_TILES);

    // issue BOTH tiles' x loads before any compute (16 independent loads)
    floatx4 xA[8], xB[8];
    if (vA) {
        const float* xr = x + (size_t)(tA * 16 + m) * D_IN + quad * 8;
        #pragma unroll
        for (int kc = 0; kc < 4; ++kc) {
            xA[2*kc]   = *(const floatx4*)(xr + kc * 32);
            xA[2*kc+1] = *(const floatx4*)(xr + kc * 32 + 4);
        }
    }
    if (vB) {
        const float* xr = x + (size_t)(tB * 16 + m) * D_IN + quad * 8;
        #pragma unroll
        for (int kc = 0; kc < 4; ++kc) {
            xB[2*kc]   = *(const floatx4*)(xr + kc * 32);
            xB[2*kc+1] = *(const floatx4*)(xr + kc * 32 + 4);
        }
    }

    #pragma unroll
    for (int half = 0; half < 2; ++half) {
        const bool valid = half ? vB : vA;
        if (!valid) continue;
        const int tile = half ? tB : tA;
        const floatx4* xs = half ? xB : xA;
        const int mbase = tile * 16;

        short8 ahi[4], alo[4];
        #pragma unroll
        for (int kc = 0; kc < 4; ++kc) {
            floatx4 v0 = xs[2*kc], v1 = xs[2*kc+1];
            float f[8] = {v0.x, v0.y, v0.z, v0.w, v1.x, v1.y, v1.z, v1.w};
            #pragma unroll
            for (int j = 0; j < 8; ++j) {
                unsigned short hi = f2bf(f[j]);
                float lo = f[j] - bf2f(hi);
                ahi[kc][j] = (short)hi;
                alo[kc][j] = (short)f2bf(lo);
            }
        }

        floatx4 acc[4] = {{0.f,0.f,0.f,0.f},{0.f,0.f,0.f,0.f},{0.f,0.f,0.f,0.f},{0.f,0.f,0.f,0.f}};
        #pragma unroll
        for (int kc = 0; kc < 4; ++kc) {
            #pragma unroll
            for (int nt = 0; nt < 4; ++nt) {
                int fo = ((kc * 4 + nt) * 64 + lane) * 8;
                short8 bhi = *(const short8*)&bhi_lds[fo];
                short8 blo = *(const short8*)&blo_lds[fo];
                acc[nt] = __builtin_amdgcn_mfma_f32_16x16x32_bf16(ahi[kc], bhi, acc[nt], 0, 0, 0);
                acc[nt] = __builtin_amdgcn_mfma_f32_16x16x32_bf16(ahi[kc], blo, acc[nt], 0, 0, 0);
                acc[nt] = __builtin_amdgcn_mfma_f32_16x16x32_bf16(alo[kc], bhi, acc[nt], 0, 0, 0);
            }
        }

        // raw f32 write; dinv scale + bf16 quantization deferred to build
        #pragma unroll
        for (int nt = 0; nt < 4; ++nt) {
            int col = nt * 16 + m;
            #pragma unroll
            for (int r = 0; r < 4; ++r) {
                int row = mbase + quad * 4 + r;
                h_raw[(size_t)row * D_H + col] = acc[nt][r];
            }
        }
    }
}

// Pass 2: one block per bucket. Computes its own base via masked block
// reduction over the 512 bucket counts. Local hist+scan over 196 nodes ->
// offsets/dinv, sort entries in LDS, write CSR segment SEQUENTIALLY.
// Also applies the dinv scale to this bucket's h_raw rows, producing the
// bf16 hs that agg1 gathers (bit-identical to r3's gemm1 output).
__global__ __launch_bounds__(256) void build_kernel(const int* __restrict__ cursors,
                                                    const int* __restrict__ region,
                                                    int* __restrict__ offsets,
                                                    float* __restrict__ dinv,
                                                    int* __restrict__ srcs,
                                                    const float* __restrict__ h_raw,
                                                    unsigned short* __restrict__ hs) {
    __shared__ int lhist[NPB];        // counts, then running cursors
    __shared__ int lscan[NPB + 1];
    __shared__ int sbuf[256];
    __shared__ int srt[BCAP];
    __shared__ int red[4];
    __shared__ float sdv[NPB];
    int b = blockIdx.x;
    int t = threadIdx.x;

    // base = sum of cursors[i] for i < b  (masked reduction, 512 counts)
    int c0 = cursors[t];
    int c1 = cursors[t + 256];
    int p = ((t < b) ? c0 : 0) + ((t + 256 < b) ? c1 : 0);
    int lane = t & 63, wid = t >> 6;
    #pragma unroll
    for (int off = 32; off > 0; off >>= 1) p += __shfl_down(p, off);
    if (lane == 0) red[wid] = p;
    __syncthreads();
    int base = red[0] + red[1] + red[2] + red[3];
    int cnt = cursors[b];
    const int* reg = region + b * BCAP;

    for (int i = t; i < NPB; i += 256) lhist[i] = 0;
    __syncthreads();
    for (int i = t; i < cnt; i += 256) {
        int ln = reg[i] >> 17;
        atomicAdd(&lhist[ln], 1);
    }
    __syncthreads();
    // exclusive scan of lhist[0..NPB-1]
    int v = (t < NPB) ? lhist[t] : 0;
    sbuf[t] = v;
    __syncthreads();
    for (int off = 1; off < 256; off <<= 1) {
        int u = (t >= off) ? sbuf[t - off] : 0;
        __syncthreads();
        sbuf[t] += u;
        __syncthreads();
    }
    int incl = sbuf[t];
    if (t < NPB) lscan[t] = incl - v;
    if (t == NPB - 1) lscan[NPB] = incl;
    __syncthreads();
    if (t < NPB) lhist[t] = incl - v;   // running cursor = exclusive scan
    __syncthreads();

    // offsets + dinv for this bucket's node range
    int node0 = b * NPB;
    int nlim = N_NODES - node0;
    if (nlim > NPB) nlim = NPB;
    if (t < nlim) {
        offsets[node0 + t] = base + lscan[t];
        int c = lscan[t + 1] - lscan[t];
        float dvv = rsqrtf((float)c + 1.0f);   // +1 self loop
        dinv[node0 + t] = dvv;
        sdv[t] = dvv;
    }
    if (b == (N_NODES - 1) / NPB && t == 0) offsets[N_NODES] = base + cnt;

    // place entries into sorted LDS buffer
    for (int i = t; i < cnt; i += 256) {
        int pk = reg[i];
        int ln = pk >> 17;
        int pos = atomicAdd(&lhist[ln], 1);
        srt[pos] = pk & 0x1FFFF;
    }
    __syncthreads();   // also guarantees sdv[] fully written
    // sequential write-out (coalesced full lines)
    for (int i = t; i < cnt; i += 256) srcs[base + i] = srt[i];

    // scale this bucket's h rows: hs = f2bf(h_raw * dinv)  (single rounding,
    // identical to r3's in-gemm scale). Coalesced: 196*64 f32 reads/block.
    int tot = nlim * D_H;
    for (int i = t; i < tot; i += 256) {
        int r = i >> 6;            // 0..nlim-1
        int c = i & 63;
        size_t off = (size_t)(node0 + r) * D_H + c;
        hs[off] = f2bf(h_raw[off] * sdv[r]);
    }
}

// Fused layer-1 aggregation + ReLU + layer-2 linear (r3-proven structure).
// 16 lanes per node, 4 bf16 columns per lane; hs PRE-SCALED by dinv[src].
// NOTE (r8 lesson): gather loop is AT its compulsory-traffic floor
// (~90 MB = 8 XCDs x 86.5K expected-distinct 128B rows) at the ~2.3-2.5 TB/s
// random-line L2-miss service rate. Do not restructure further.
// r12 change: h2s is written as BF16 (f2bf(p*dv)) — halves agg2's
// compulsory line traffic (64B -> 32B rows; 4 rows per 128B line).
__global__ __launch_bounds__(256) void agg1_fused_kernel(const unsigned short* __restrict__ hs,
                                                         const int* __restrict__ offsets,
                                                         const int* __restrict__ srcs,
                                                         const float* __restrict__ dinv,
                                                         const float* __restrict__ b1,
                                                         const float* __restrict__ W2,
                                                         unsigned short* __restrict__ h2s) {
    __shared__ float w2t[16 * 68];   // w2t[c*68 + j] = W2[j*16 + c]
    __shared__ float rbuf[16 * 68];  // per group: 68-float stride (64 used)

    const int tid = threadIdx.x;
    // stage W2 transposed (once per block)
    for (int i = tid; i < 1024; i += 256) {
        int j = i >> 4, c = i & 15;
        w2t[c * 68 + j] = W2[i];
    }

    const int g    = tid >> 4;              // group within block, 0..15
    const int sl   = tid & 15;              // sublane within group
    const int node = blockIdx.x * 16 + g;   // 6250*16 == 100000 exact
    const int c4   = sl * 4;                // column base (of 64)

    const int beg = offsets[node];
    const int end = offsets[node + 1];

    // self-loop init: 4 bf16 cols of own (pre-scaled) row
    ushort4 s4v = *(const ushort4*)(hs + (size_t)node * D_H + c4);
    float a0 = bf2f(s4v.x), a1 = bf2f(s4v.y), a2 = bf2f(s4v.z), a3 = bf2f(s4v.w);

    for (int e = beg; e < end; e += 16) {
        int rem = end - e;
        int idx = srcs[e + sl];            // coalesced 64B per group; pad-safe
        #pragma unroll
        for (int k = 0; k < 16; ++k) {
            int j = __shfl(idx, k, 16);    // broadcast within 16-lane group
            ushort4 v = *(const ushort4*)(hs + (size_t)j * D_H + c4);
            float m = (k < rem) ? 1.0f : 0.0f;
            a0 = fmaf(bf2f(v.x), m, a0);
            a1 = fmaf(bf2f(v.y), m, a1);
            a2 = fmaf(bf2f(v.z), m, a2);
            a3 = fmaf(bf2f(v.w), m, a3);
        }
    }

    const float dv = dinv[node];
    const floatx4 bb = *(const floatx4*)(b1 + c4);
    float* rb = rbuf + g * 68;
    rb[c4 + 0] = fmaxf(a0 * dv + bb.x, 0.f);
    rb[c4 + 1] = fmaxf(a1 * dv + bb.y, 0.f);
    rb[c4 + 2] = fmaxf(a2 * dv + bb.z, 0.f);
    rb[c4 + 3] = fmaxf(a3 * dv + bb.w, 0.f);
    __syncthreads();   // single pass per thread -> block-wide barrier is safe

    // out[node][sl] = sum_j r[j] * W2[j][sl]   (then * dv), stored bf16
    float p = 0.f;
    #pragma unroll
    for (int t4 = 0; t4 < 16; ++t4) {
        floatx4 rv = *(const floatx4*)(rb + 4 * t4);
        floatx4 wv = *(const floatx4*)(&w2t[sl * 68 + 4 * t4]);
        p += rv.x * wv.x + rv.y * wv.y + rv.z * wv.z + rv.w * wv.w;
    }
    h2s[node * D_OUT + sl] = f2bf(p * dv);
}

// out[i][c] = dinv[i]*(h2s[i][c] + sum_{j->i} h2s[j][c]) + b2[c]
// 16 threads per node; padded srcs (no clamp), fmac-masked 16-wide batches.
// h2s is bf16 (32B rows): compulsory random-line traffic halves vs f32.
// Accumulation stays f32.
__global__ __launch_bounds__(256) void agg2_kernel(const unsigned short* __restrict__ h2s,
                                                   const int* __restrict__ offsets,
                                                   const int* __restrict__ srcs,
                                                   const float* __restrict__ dinv,
                                                   const float* __restrict__ b2,
                                                   float* __restrict__ out) {
    int col = threadIdx.x & 15;
    int nidx = (blockIdx.x * blockDim.x + threadIdx.x) >> 4;
    int stride = (gridDim.x * blockDim.x) >> 4;
    for (int node = nidx; node < N_NODES; node += stride) {
        int beg = offsets[node], end = offsets[node + 1];
        float acc = bf2f(h2s[node * D_OUT + col]);  // self loop
        for (int e = beg; e < end; e += 16) {
            int rem = end - e;
            const int* ep = srcs + e;
            int jj[16];
            #pragma unroll
            for (int k = 0; k < 16; ++k) jj[k] = ep[k];
            float vv[16];
            #pragma unroll
            for (int k = 0; k < 16; ++k) vv[k] = bf2f(h2s[jj[k] * D_OUT + col]);
            #pragma unroll
            for (int k = 0; k < 16; ++k) {
                float m = (k < rem) ? 1.0f : 0.0f;
                acc = fmaf(vv[k], m, acc);
            }
        }
        out[node * D_OUT + col] = acc * dinv[node] + b2[col];
    }
}

extern "C" void kernel_launch(void* const* d_in, const int* in_sizes, int n_in,
                              void* d_out, int out_size, void* d_ws, size_t ws_size,
                              hipStream_t stream) {
    const float* x  = (const float*)d_in[0];
    const int*   ei = (const int*)d_in[1];
    const float* W1 = (const float*)d_in[2];
    const float* b1 = (const float*)d_in[3];
    const float* W2 = (const float*)d_in[4];
    const float* b2 = (const float*)d_in[5];
    float* out = (float*)d_out;

    const int* src = ei;             // edge_index[0]
    const int* dst = ei + N_EDGES;   // edge_index[1]

    char* w = (char*)d_ws;
    int*   cursors  = (int*)(w + 0);
    int*   offsets  = (int*)(w + 4096);
    float* dinv     = (float*)(w + 404224);
    int*   srcs     = (int*)(w + 804224);
    unsigned short* hs  = (unsigned short*)(w + 7204352);
    unsigned short* h2s = (unsigned short*)(w + 20004480);
    int*   region   = (int*)(w + 26404480);
    float* h_raw    = (float*)(w + 34793088);

    zero_small_kernel<<<1, 512, 0, stream>>>(cursors, srcs);
    fused_bin_gemm1_kernel<<<FUSED_T, 256, FUSED_LDS, stream>>>(
        src, dst, cursors, region, x, W1, h_raw);
    build_kernel<<<NBKT, 256, 0, stream>>>(cursors, region, offsets, dinv, srcs,
                                           h_raw, hs);
    agg1_fused_kernel<<<6250, 256, 0, stream>>>(hs, offsets, srcs, dinv, b1, W2, h2s);
    agg2_kernel<<<6250, 256, 0, stream>>>(h2s, offsets, srcs, dinv, b2, out);
}